// Round 12
// baseline (554.252 us; speedup 1.0000x reference)
//
#include <hip/hip_runtime.h>
#include <hip/hip_bf16.h>
#include <math.h>

typedef __bf16 bf16;
typedef __bf16 bf16x8 __attribute__((ext_vector_type(8)));
typedef float f32x4 __attribute__((ext_vector_type(4)));
typedef short short8 __attribute__((ext_vector_type(8)));

#define E_ 768
#define S_ 1024
#define BT_ 16
#define KM_ 12
#define KX_ 24
#define NPOS_ 4608
#define NB_ 12

// compile-time twiddles: C32d[j]=cos(2*pi*j/32), S32d[j]=sin(2*pi*j/32).
// Indexed with wave-uniform (and, after unrolling, compile-time) j -> no trig,
// no LDS, no serial recurrence chain.
__device__ const float C32d[32] = {
    1.0f,  0.980785280f,  0.923879533f,  0.831469612f,  0.707106781f,  0.555570233f,  0.382683432f,  0.195090322f,
    0.0f, -0.195090322f, -0.382683432f, -0.555570233f, -0.707106781f, -0.831469612f, -0.923879533f, -0.980785280f,
   -1.0f, -0.980785280f, -0.923879533f, -0.831469612f, -0.707106781f, -0.555570233f, -0.382683432f, -0.195090322f,
    0.0f,  0.195090322f,  0.382683432f,  0.555570233f,  0.707106781f,  0.831469612f,  0.923879533f,  0.980785280f
};
__device__ const float S32d[32] = {
    0.0f,  0.195090322f,  0.382683432f,  0.555570233f,  0.707106781f,  0.831469612f,  0.923879533f,  0.980785280f,
    1.0f,  0.980785280f,  0.923879533f,  0.831469612f,  0.707106781f,  0.555570233f,  0.382683432f,  0.195090322f,
    0.0f, -0.195090322f, -0.382683432f, -0.555570233f, -0.707106781f, -0.831469612f, -0.923879533f, -0.980785280f,
   -1.0f, -0.980785280f, -0.923879533f, -0.831469612f, -0.707106781f, -0.555570233f, -0.382683432f, -0.195090322f
};

// tanh-form gelu, ~10 VALU ops (2 transcendental) vs erff's ~30.
__device__ __forceinline__ float gelu_fast(float x) {
    float t = x * x;
    float u = x * fmaf(t, 0.0356774081f, 0.7978845608f);  // 0.79788456*(x + 0.044715 x^3)
    float e = __expf(2.0f * u);
    float th = fmaf(-2.0f, __fdividef(1.0f, e + 1.0f), 1.0f);  // tanh(u)
    float hx = 0.5f * x;
    return fmaf(hx, th, hx);
}

// negate 8 bf16 lanes (flip sign bits) — MFMA has no subtract-accumulate
__device__ __forceinline__ bf16x8 neg8(bf16x8 v) {
    short8 s;
    __builtin_memcpy(&s, &v, 16);
    s ^= (short)0x8000;
    bf16x8 r;
    __builtin_memcpy(&r, &s, 16);
    return r;
}

// async global->LDS, 16B per lane. LDS dest is wave-uniform base + lane*16;
// global src is per-lane.
__device__ __forceinline__ void gload16(bf16* lds, const bf16* g) {
    __builtin_amdgcn_global_load_lds(
        (const __attribute__((address_space(1))) void*)g,
        (__attribute__((address_space(3))) void*)lds,
        16, 0, 0);
}

// ---------------- LN1 stats: wave-per-row (4 rows/block), float4 loads, no LDS ----------------
__global__ __launch_bounds__(256) void k_ln_stats(const float* __restrict__ x,
                                                  float* __restrict__ mu, float* __restrict__ rs) {
    int w = threadIdx.x >> 6, l = threadIdx.x & 63;
    int row = blockIdx.x * 4 + w;
    const float4* p = (const float4*)(x + (size_t)row * E_ + l * 12);
    float4 a = p[0], b = p[1], c = p[2];
    float s  = a.x + a.y + a.z + a.w + b.x + b.y + b.z + b.w + c.x + c.y + c.z + c.w;
    float ss = a.x*a.x + a.y*a.y + a.z*a.z + a.w*a.w
             + b.x*b.x + b.y*b.y + b.z*b.z + b.w*b.w
             + c.x*c.x + c.y*c.y + c.z*c.z + c.w*c.w;
    #pragma unroll
    for (int off = 32; off > 0; off >>= 1) {
        s  += __shfl_xor(s, off);
        ss += __shfl_xor(ss, off);
    }
    if (l == 0) {
        float m = s * (1.0f / E_);
        float var = ss * (1.0f / E_) - m * m;
        mu[row] = m;
        rs[row] = rsqrtf(var + 1e-5f);
    }
}

// ---------------- full LayerNorm (ln2) -> bf16: wave-per-row, vectorized ----------------
__global__ __launch_bounds__(256) void k_ln2(const float* __restrict__ x,
                                             const float* __restrict__ g,
                                             const float* __restrict__ b,
                                             bf16* __restrict__ out) {
    int w = threadIdx.x >> 6, l = threadIdx.x & 63;
    int row = blockIdx.x * 4 + w;
    int e0 = l * 12;
    const float4* p = (const float4*)(x + (size_t)row * E_ + e0);
    float4 va = p[0], vb = p[1], vc = p[2];
    float v[12] = {va.x, va.y, va.z, va.w, vb.x, vb.y, vb.z, vb.w, vc.x, vc.y, vc.z, vc.w};
    float s = 0.f, ss = 0.f;
    #pragma unroll
    for (int j = 0; j < 12; j++) { s += v[j]; ss += v[j] * v[j]; }
    #pragma unroll
    for (int off = 32; off > 0; off >>= 1) {
        s  += __shfl_xor(s, off);
        ss += __shfl_xor(ss, off);
    }
    float m = s * (1.0f / E_);
    float var = ss * (1.0f / E_) - m * m;
    float r = rsqrtf(var + 1e-5f);
    const float4* gp = (const float4*)(g + e0);
    const float4* bp = (const float4*)(b + e0);
    float4 g0 = gp[0], g1 = gp[1], g2 = gp[2];
    float4 b0 = bp[0], b1 = bp[1], b2 = bp[2];
    float gg[12] = {g0.x, g0.y, g0.z, g0.w, g1.x, g1.y, g1.z, g1.w, g2.x, g2.y, g2.z, g2.w};
    float bbv[12] = {b0.x, b0.y, b0.z, b0.w, b1.x, b1.y, b1.z, b1.w, b2.x, b2.y, b2.z, b2.w};
    bf16 ov[12];
    #pragma unroll
    for (int j = 0; j < 12; j++) ov[j] = (bf16)((v[j] - m) * r * gg[j] + bbv[j]);
    bf16* op = out + (size_t)row * E_ + e0;
    *(uint2*)(op)     = *(uint2*)&ov[0];
    *(uint2*)(op + 4) = *(uint2*)&ov[4];
    *(uint2*)(op + 8) = *(uint2*)&ov[8];
}

// ---------------- forward DFT along y (12 modes), LN1 fused; register data + const tables ----------------
__global__ __launch_bounds__(256) void k_dft_y(const float* __restrict__ inp,
                                               const float* __restrict__ mu, const float* __restrict__ rs,
                                               const float* __restrict__ g, const float* __restrict__ bb,
                                               float* __restrict__ gre, float* __restrict__ gim) {
    int bid = blockIdx.x;                 // BT_*32*3
    int ec = bid % 3, x = (bid / 3) % 32, bt = bid / 96;
    int t = threadIdx.x;
    int e = ec * 256 + t;
    float gv = g[e], bv = bb[e];
    int row0 = bt * S_ + x * 32;
    const float* base = inp + (size_t)row0 * E_ + e;
    float v[32];
    #pragma unroll
    for (int y = 0; y < 32; y++) {
        float m = mu[row0 + y], r = rs[row0 + y];
        v[y] = (base[(size_t)y * E_] - m) * r * gv + bv;
    }
    #pragma unroll
    for (int ky = 0; ky < KM_; ky++) {
        float re = 0.f, ims = 0.f;
        #pragma unroll
        for (int y = 0; y < 32; y++) {
            int j = (ky * y) & 31;
            re  = fmaf(v[y], C32d[j], re);
            ims = fmaf(v[y], S32d[j], ims);
        }
        size_t o = ((size_t)((bt * 32 + x) * KM_ + ky)) * E_ + e;
        gre[o] = re; gim[o] = -ims;       // e^{-i...}: im = -sum(v*sin)
    }
}

// ---------------- forward DFT along x (kx=5..28), scale 1/32; register data + const tables ----------------
__global__ __launch_bounds__(256) void k_dft_x(const float* __restrict__ gre, const float* __restrict__ gim,
                                               float* __restrict__ fr, float* __restrict__ fi) {
    int bid = blockIdx.x;                 // BT_*KM_*3
    int ec = bid % 3, ky = (bid / 3) % KM_, bt = bid / (3 * KM_);
    int t = threadIdx.x;
    int eo = ec * 256 + t;
    float gr[32], gi[32];
    #pragma unroll
    for (int x = 0; x < 32; x++) {
        size_t o = ((size_t)((bt * 32 + x) * KM_ + ky)) * E_ + eo;
        gr[x] = gre[o]; gi[x] = gim[o];
    }
    #pragma unroll
    for (int kxi = 0; kxi < KX_; kxi++) {
        int kx = kxi + 5;
        float re = 0.f, im = 0.f;
        #pragma unroll
        for (int x = 0; x < 32; x++) {
            int j = (kx * x) & 31;
            float c = C32d[j], s = S32d[j];
            re = fmaf(gr[x], c, re);      // (gr+i*gi)*(c - i*s)
            re = fmaf(gi[x], s, re);
            im = fmaf(gi[x], c, im);
            im = fmaf(-gr[x], s, im);
        }
        size_t p = (size_t)(bt * KX_ + kxi) * KM_ + ky;
        fr[p * E_ + eo] = re * (1.0f / 32.0f);
        fi[p * E_ + eo] = im * (1.0f / 32.0f);
    }
}

// ---------------- MFMA block-diagonal complex 2-layer MLP + softshrink (in-place fr/fi) ----------------
__global__ __launch_bounds__(256) void k_blockmlp(float* fr, float* fi,
                                                  const float* __restrict__ w1, const float* __restrict__ b1,
                                                  const float* __restrict__ w2, const float* __restrict__ b2) {
    int n = blockIdx.x / 36;
    int p0 = (blockIdx.x % 36) * 128;
    int t = threadIdx.x;
    __shared__ __align__(16) bf16 lXr[128 * 72];
    __shared__ __align__(16) bf16 lXi[128 * 72];
    __shared__ __align__(16) bf16 lW1a[64 * 72];
    __shared__ __align__(16) bf16 lW1b[64 * 72];
    __shared__ __align__(16) bf16 lW2a[64 * 72];
    __shared__ __align__(16) bf16 lW2b[64 * 72];

    {
        int o = t & 63, iq = t >> 6;
        const float* s1a = w1 + (size_t)n * 4096;
        const float* s1b = w1 + (size_t)(NB_ + n) * 4096;
        const float* s2a = w2 + (size_t)n * 4096;
        const float* s2b = w2 + (size_t)(NB_ + n) * 4096;
        #pragma unroll
        for (int ii = 0; ii < 16; ii++) {
            int i = iq * 16 + ii;
            lW1a[o * 72 + i] = (bf16)s1a[i * 64 + o];
            lW1b[o * 72 + i] = (bf16)s1b[i * 64 + o];
            lW2a[o * 72 + i] = (bf16)s2a[i * 64 + o];
            lW2b[o * 72 + i] = (bf16)s2b[i * 64 + o];
        }
    }
    {
        int ch4 = (t & 15) * 4, prow = t >> 4;
        #pragma unroll
        for (int rep = 0; rep < 8; rep++) {
            int p = rep * 16 + prow;
            size_t ga = (size_t)(p0 + p) * E_ + n * 64 + ch4;
            float4 vr = *(const float4*)&fr[ga];
            float4 vi = *(const float4*)&fi[ga];
            bf16 br[4] = {(bf16)vr.x, (bf16)vr.y, (bf16)vr.z, (bf16)vr.w};
            bf16 bi[4] = {(bf16)vi.x, (bf16)vi.y, (bf16)vi.z, (bf16)vi.w};
            *(uint2*)&lXr[p * 72 + ch4] = *(uint2*)br;
            *(uint2*)&lXi[p * 72 + ch4] = *(uint2*)bi;
        }
    }
    int w = t >> 6, l = t & 63, lr = l & 15, lq = l >> 4;
    float bias1r[4], bias1i[4], bias2r[4], bias2i[4];
    #pragma unroll
    for (int ni = 0; ni < 4; ni++) {
        int o = n * 64 + ni * 16 + lr;
        bias1r[ni] = b1[o]; bias1i[ni] = b1[NB_ * 64 + o];
        bias2r[ni] = b2[o]; bias2i[ni] = b2[NB_ * 64 + o];
    }
    __syncthreads();

    f32x4 a1r[2][4], a1i[2][4];
    #pragma unroll
    for (int mt = 0; mt < 2; mt++)
        #pragma unroll
        for (int ni = 0; ni < 4; ni++) { a1r[mt][ni] = (f32x4){0,0,0,0}; a1i[mt][ni] = (f32x4){0,0,0,0}; }
    #pragma unroll
    for (int ks = 0; ks < 2; ks++) {
        int k0 = ks * 32;
        bf16x8 xr[2], xi[2], xin[2];
        #pragma unroll
        for (int mt = 0; mt < 2; mt++) {
            int row = w * 32 + mt * 16 + lr;
            xr[mt]  = *(bf16x8*)&lXr[row * 72 + k0 + lq * 8];
            xi[mt]  = *(bf16x8*)&lXi[row * 72 + k0 + lq * 8];
            xin[mt] = neg8(xi[mt]);
        }
        #pragma unroll
        for (int ni = 0; ni < 4; ni++) {
            bf16x8 ba = *(bf16x8*)&lW1a[(ni * 16 + lr) * 72 + k0 + lq * 8];
            bf16x8 bb = *(bf16x8*)&lW1b[(ni * 16 + lr) * 72 + k0 + lq * 8];
            #pragma unroll
            for (int mt = 0; mt < 2; mt++) {
                a1r[mt][ni] = __builtin_amdgcn_mfma_f32_16x16x32_bf16(xr[mt],  ba, a1r[mt][ni], 0, 0, 0);
                a1r[mt][ni] = __builtin_amdgcn_mfma_f32_16x16x32_bf16(xin[mt], bb, a1r[mt][ni], 0, 0, 0);
                a1i[mt][ni] = __builtin_amdgcn_mfma_f32_16x16x32_bf16(xi[mt],  ba, a1i[mt][ni], 0, 0, 0);
                a1i[mt][ni] = __builtin_amdgcn_mfma_f32_16x16x32_bf16(xr[mt],  bb, a1i[mt][ni], 0, 0, 0);
            }
        }
    }
    #pragma unroll
    for (int mt = 0; mt < 2; mt++)
        #pragma unroll
        for (int ni = 0; ni < 4; ni++) {
            int o = ni * 16 + lr;
            #pragma unroll
            for (int r = 0; r < 4; r++) {
                int row = w * 32 + mt * 16 + lq * 4 + r;
                lXr[row * 72 + o] = (bf16)gelu_fast(a1r[mt][ni][r] + bias1r[ni]);
                lXi[row * 72 + o] = (bf16)gelu_fast(a1i[mt][ni][r] + bias1i[ni]);
            }
        }

    f32x4 a2r[2][4], a2i[2][4];
    #pragma unroll
    for (int mt = 0; mt < 2; mt++)
        #pragma unroll
        for (int ni = 0; ni < 4; ni++) { a2r[mt][ni] = (f32x4){0,0,0,0}; a2i[mt][ni] = (f32x4){0,0,0,0}; }
    #pragma unroll
    for (int ks = 0; ks < 2; ks++) {
        int k0 = ks * 32;
        bf16x8 xr[2], xi[2], xin[2];
        #pragma unroll
        for (int mt = 0; mt < 2; mt++) {
            int row = w * 32 + mt * 16 + lr;
            xr[mt]  = *(bf16x8*)&lXr[row * 72 + k0 + lq * 8];
            xi[mt]  = *(bf16x8*)&lXi[row * 72 + k0 + lq * 8];
            xin[mt] = neg8(xi[mt]);
        }
        #pragma unroll
        for (int ni = 0; ni < 4; ni++) {
            bf16x8 ba = *(bf16x8*)&lW2a[(ni * 16 + lr) * 72 + k0 + lq * 8];
            bf16x8 bb = *(bf16x8*)&lW2b[(ni * 16 + lr) * 72 + k0 + lq * 8];
            #pragma unroll
            for (int mt = 0; mt < 2; mt++) {
                a2r[mt][ni] = __builtin_amdgcn_mfma_f32_16x16x32_bf16(xr[mt],  ba, a2r[mt][ni], 0, 0, 0);
                a2r[mt][ni] = __builtin_amdgcn_mfma_f32_16x16x32_bf16(xin[mt], bb, a2r[mt][ni], 0, 0, 0);
                a2i[mt][ni] = __builtin_amdgcn_mfma_f32_16x16x32_bf16(xi[mt],  ba, a2i[mt][ni], 0, 0, 0);
                a2i[mt][ni] = __builtin_amdgcn_mfma_f32_16x16x32_bf16(xr[mt],  bb, a2i[mt][ni], 0, 0, 0);
            }
        }
    }
    #pragma unroll
    for (int mt = 0; mt < 2; mt++)
        #pragma unroll
        for (int ni = 0; ni < 4; ni++) {
            int o = ni * 16 + lr;
            #pragma unroll
            for (int r = 0; r < 4; r++) {
                int row = w * 32 + mt * 16 + lq * 4 + r;
                float vr = a2r[mt][ni][r] + bias2r[ni];
                float vi = a2i[mt][ni][r] + bias2i[ni];
                vr = (vr > 0.01f) ? vr - 0.01f : ((vr < -0.01f) ? vr + 0.01f : 0.0f);
                vi = (vi > 0.01f) ? vi - 0.01f : ((vi < -0.01f) ? vi + 0.01f : 0.0f);
                size_t ga = (size_t)(p0 + row) * E_ + n * 64 + o;
                fr[ga] = vr;
                fi[ga] = vi;
            }
        }
}

// ---------------- inverse DFT along x (24 modes -> 32 x); register data + const tables ----------------
__global__ __launch_bounds__(256) void k_idft_x(const float* __restrict__ pr_, const float* __restrict__ pi_,
                                                float* __restrict__ zre, float* __restrict__ zim) {
    int bid = blockIdx.x;                 // BT_*KM_*3
    int ec = bid % 3, ky = (bid / 3) % KM_, bt = bid / (3 * KM_);
    int t = threadIdx.x;
    int eo = ec * 256 + t;
    float pr[KX_], pi[KX_];
    #pragma unroll
    for (int kxi = 0; kxi < KX_; kxi++) {
        size_t p = (size_t)(bt * KX_ + kxi) * KM_ + ky;
        pr[kxi] = pr_[p * E_ + eo];
        pi[kxi] = pi_[p * E_ + eo];
    }
    #pragma unroll
    for (int x = 0; x < 32; x++) {
        float re = 0.f, im = 0.f;
        #pragma unroll
        for (int kxi = 0; kxi < KX_; kxi++) {
            int j = ((kxi + 5) * x) & 31;
            float c = C32d[j], s = S32d[j];
            re = fmaf(pr[kxi], c, re);    // (pr+i*pi)*(c + i*s)
            re = fmaf(-pi[kxi], s, re);
            im = fmaf(pr[kxi], s, im);
            im = fmaf(pi[kxi], c, im);
        }
        size_t zo = ((size_t)((bt * 32 + x) * KM_ + ky)) * E_ + eo;
        zre[zo] = re; zim[zo] = im;
    }
}

// ---------------- inverse rfft along y + residuals; register data + const tables ----------------
__global__ __launch_bounds__(256) void k_idft_y_res(const float* __restrict__ zre, const float* __restrict__ zim,
                                                    const float* __restrict__ inp,
                                                    const float* __restrict__ mu, const float* __restrict__ rs,
                                                    const float* __restrict__ g, const float* __restrict__ bb,
                                                    float* __restrict__ out) {
    int bid = blockIdx.x;                 // BT_*32*3
    int ec = bid % 3, x = (bid / 3) % 32, bt = bid / 96;
    int t = threadIdx.x;
    int e = ec * 256 + t;
    float zr[KM_], zi[KM_];
    #pragma unroll
    for (int ky = 0; ky < KM_; ky++) {
        size_t zo = ((size_t)((bt * 32 + x) * KM_ + ky)) * E_ + e;
        zr[ky] = zre[zo];
        zi[ky] = zim[zo];
    }
    float gv = g[e], bv = bb[e];
    int row0 = bt * S_ + x * 32;
    #pragma unroll
    for (int y = 0; y < 32; y++) {
        float v = zr[0];                  // ky=0: Re only (irfft drops Im of DC)
        #pragma unroll
        for (int ky = 1; ky < KM_; ky++) {
            int j = (ky * y) & 31;
            v = fmaf(zr[ky], 2.0f * C32d[j], v);
            v = fmaf(zi[ky], -2.0f * S32d[j], v);
        }
        v *= (1.0f / 32.0f);
        size_t o = (size_t)(row0 + y) * E_ + e;
        float iv = inp[o];
        float m = mu[row0 + y], r = rs[row0 + y];
        out[o] = v + ((iv - m) * r * gv + bv) + iv;
    }
}

// ---------------- fp32 [R][C] -> bf16 [C][R] transpose+cast ----------------
__global__ void k_transpose_cast(const float* __restrict__ src, bf16* __restrict__ dst, int R, int C) {
    __shared__ float tile[32][33];
    int c0 = blockIdx.x * 32, r0 = blockIdx.y * 32;
    int tx = threadIdx.x, ty = threadIdx.y;
    #pragma unroll
    for (int j = 0; j < 32; j += 8)
        tile[ty + j][tx] = src[(size_t)(r0 + ty + j) * C + c0 + tx];
    __syncthreads();
    #pragma unroll
    for (int j = 0; j < 32; j += 8)
        dst[(size_t)(c0 + ty + j) * R + r0 + tx] = (bf16)tile[tx][ty + j];
}

// ---------------- bf16 MFMA GEMM, 256x256 tile, BK=64, counted-vmcnt pipeline ----------------
// (round-5 kernel, verified: 0 bank conflicts, passed. Used for GEMM1.)
template<bool FUSE_GELU>
__global__ __launch_bounds__(512, 2) void k_gemm(const bf16* __restrict__ A, const bf16* __restrict__ Bt,
                                                 const float* __restrict__ bias, int M, int N, int K,
                                                 bf16* __restrict__ outb, float* __restrict__ outf) {
    __shared__ __align__(16) bf16 lA[2][256 * 64];
    __shared__ __align__(16) bf16 lB[2][256 * 64];
    int t = threadIdx.x;
    int m0 = blockIdx.x * 256, n0 = blockIdx.y * 256;
    int w = t >> 6, l = t & 63;
    int wm = (w >> 2) * 128, wn = (w & 3) * 64;
    int lr = l & 15, lq = l >> 4;
    int s0 = (lq ^ (lr & 7)) * 8;          // phys 16B-slot for ks=0, in bf16 elems
    int s1 = s0 ^ 32;                      // ks=1: logical slot +4 -> XOR bit2 (32 elems)

    int sil  = w * 8 + (l >> 3);           // row within line
    int gcol = ((l & 7) ^ ((l >> 3) & 7)) * 8;
    const bf16* pa = A  + (size_t)(m0 + sil) * K + gcol;
    const bf16* pb = Bt + (size_t)(n0 + sil) * K + gcol;
    int lofs = (w * 8) * 64;               // wave-uniform LDS base (elems)

    f32x4 acc[8][4];
    #pragma unroll
    for (int i = 0; i < 8; i++)
        #pragma unroll
        for (int j = 0; j < 4; j++)
            acc[i][j] = (f32x4){0.f, 0.f, 0.f, 0.f};

    int nk = K / 64;
#define STAGE_T(T, d) do { const size_t _ko = (size_t)(T) * 64;                  \
        gload16(&lA[d][lofs],            pa + _ko);                              \
        gload16(&lA[d][lofs + 4096],     pa + (size_t)64  * K + _ko);            \
        gload16(&lA[d][lofs + 8192],     pa + (size_t)128 * K + _ko);            \
        gload16(&lA[d][lofs + 12288],    pa + (size_t)192 * K + _ko);            \
        gload16(&lB[d][lofs],            pb + _ko);                              \
        gload16(&lB[d][lofs + 4096],     pb + (size_t)64  * K + _ko);            \
        gload16(&lB[d][lofs + 8192],     pb + (size_t)128 * K + _ko);            \
        gload16(&lB[d][lofs + 12288],    pb + (size_t)192 * K + _ko);            \
    } while (0)

    STAGE_T(0, 0);
    STAGE_T(1, 1);
    asm volatile("s_waitcnt vmcnt(8)" ::: "memory");   // tile0 landed; tile1's 8 in flight
    __builtin_amdgcn_sched_barrier(0);
    __builtin_amdgcn_s_barrier();

    for (int kt = 0; kt < nk; kt++) {
        int d = kt & 1;
        bf16x8 a0[8], a1[8], b0[4], b1[4];
        #pragma unroll
        for (int ni = 0; ni < 4; ni++) {
            int ro = (wn + ni * 16 + lr) * 64;
            b0[ni] = *(bf16x8*)&lB[d][ro + s0];
            b1[ni] = *(bf16x8*)&lB[d][ro + s1];
        }
        #pragma unroll
        for (int mi = 0; mi < 8; mi++) {
            int ro = (wm + mi * 16 + lr) * 64;
            a0[mi] = *(bf16x8*)&lA[d][ro + s0];
            a1[mi] = *(bf16x8*)&lA[d][ro + s1];
        }
        __builtin_amdgcn_s_setprio(1);
        #pragma unroll
        for (int mi = 0; mi < 8; mi++)
            #pragma unroll
            for (int ni = 0; ni < 4; ni++)
                acc[mi][ni] = __builtin_amdgcn_mfma_f32_16x16x32_bf16(a0[mi], b0[ni], acc[mi][ni], 0, 0, 0);
        __builtin_amdgcn_s_setprio(0);
        asm volatile("s_waitcnt lgkmcnt(0)" ::: "memory");   // all 24 reads in regs
        __builtin_amdgcn_sched_barrier(0);
        __builtin_amdgcn_s_barrier();                        // dbuf[d] reads done block-wide

        if (kt + 2 < nk) STAGE_T(kt + 2, d);                 // into dead dbuf[d]
        __builtin_amdgcn_s_setprio(1);
        #pragma unroll
        for (int mi = 0; mi < 8; mi++)
            #pragma unroll
            for (int ni = 0; ni < 4; ni++)
                acc[mi][ni] = __builtin_amdgcn_mfma_f32_16x16x32_bf16(a1[mi], b1[ni], acc[mi][ni], 0, 0, 0);
        __builtin_amdgcn_s_setprio(0);
        if (kt + 1 < nk) {
            if (kt + 2 < nk) asm volatile("s_waitcnt vmcnt(8)" ::: "memory");  // tile kt+1 landed
            else             asm volatile("s_waitcnt vmcnt(0)" ::: "memory");  // tail drain
            __builtin_amdgcn_sched_barrier(0);
            __builtin_amdgcn_s_barrier();
        }
    }
#undef STAGE_T

    #pragma unroll
    for (int mi = 0; mi < 8; mi++) {
        #pragma unroll
        for (int ni = 0; ni < 4; ni++) {
            int col = n0 + wn + ni * 16 + lr;
            float bv = bias[col];
            #pragma unroll
            for (int r = 0; r < 4; r++) {
                int row = m0 + wm + mi * 16 + lq * 4 + r;
                float v = acc[mi][ni][r] + bv;
                if (FUSE_GELU) {
                    outb[(size_t)row * N + col] = (bf16)gelu_fast(v);
                } else {
                    size_t oo = (size_t)row * N + col;
                    outf[oo] = v + outf[oo];
                }
            }
        }
    }
}

// ---------------- split-K variant (GEMM2): same verified core; K-range per blockIdx.z ----------------
// Grid (M/256, N/256, KSPLIT). Each block computes acc over K[kOff, kOff+kLen) and
// atomicAdds into outf (which already holds the residual). Bias added only by kc==0.
// Rationale: GEMM2's grid was (64,3)=192 blocks @ 1 block/CU -> 25% of CUs idle.
// (64,3,4)=768 = exactly 3 full CU rounds at 100% coverage, same per-element FETCH.
__global__ __launch_bounds__(512, 2) void k_gemm_splitk(const bf16* __restrict__ A, const bf16* __restrict__ Bt,
                                                        const float* __restrict__ bias, int M, int N, int K,
                                                        int kLen, float* __restrict__ outf) {
    __shared__ __align__(16) bf16 lA[2][256 * 64];
    __shared__ __align__(16) bf16 lB[2][256 * 64];
    int t = threadIdx.x;
    int m0 = blockIdx.x * 256, n0 = blockIdx.y * 256;
    int kOff = blockIdx.z * kLen;
    int w = t >> 6, l = t & 63;
    int wm = (w >> 2) * 128, wn = (w & 3) * 64;
    int lr = l & 15, lq = l >> 4;
    int s0 = (lq ^ (lr & 7)) * 8;
    int s1 = s0 ^ 32;

    int sil  = w * 8 + (l >> 3);
    int gcol = ((l & 7) ^ ((l >> 3) & 7)) * 8;
    const bf16* pa = A  + (size_t)(m0 + sil) * K + kOff + gcol;
    const bf16* pb = Bt + (size_t)(n0 + sil) * K + kOff + gcol;
    int lofs = (w * 8) * 64;

    f32x4 acc[8][4];
    #pragma unroll
    for (int i = 0; i < 8; i++)
        #pragma unroll
        for (int j = 0; j < 4; j++)
            acc[i][j] = (f32x4){0.f, 0.f, 0.f, 0.f};

    int nk = kLen / 64;
#define STAGE_T(T, d) do { const size_t _ko = (size_t)(T) * 64;                  \
        gload16(&lA[d][lofs],            pa + _ko);                              \
        gload16(&lA[d][lofs + 4096],     pa + (size_t)64  * K + _ko);            \
        gload16(&lA[d][lofs + 8192],     pa + (size_t)128 * K + _ko);            \
        gload16(&lA[d][lofs + 12288],    pa + (size_t)192 * K + _ko);            \
        gload16(&lB[d][lofs],            pb + _ko);                              \
        gload16(&lB[d][lofs + 4096],     pb + (size_t)64  * K + _ko);            \
        gload16(&lB[d][lofs + 8192],     pb + (size_t)128 * K + _ko);            \
        gload16(&lB[d][lofs + 12288],    pb + (size_t)192 * K + _ko);            \
    } while (0)

    STAGE_T(0, 0);
    STAGE_T(1, 1);
    asm volatile("s_waitcnt vmcnt(8)" ::: "memory");
    __builtin_amdgcn_sched_barrier(0);
    __builtin_amdgcn_s_barrier();

    for (int kt = 0; kt < nk; kt++) {
        int d = kt & 1;
        bf16x8 a0[8], a1[8], b0[4], b1[4];
        #pragma unroll
        for (int ni = 0; ni < 4; ni++) {
            int ro = (wn + ni * 16 + lr) * 64;
            b0[ni] = *(bf16x8*)&lB[d][ro + s0];
            b1[ni] = *(bf16x8*)&lB[d][ro + s1];
        }
        #pragma unroll
        for (int mi = 0; mi < 8; mi++) {
            int ro = (wm + mi * 16 + lr) * 64;
            a0[mi] = *(bf16x8*)&lA[d][ro + s0];
            a1[mi] = *(bf16x8*)&lA[d][ro + s1];
        }
        __builtin_amdgcn_s_setprio(1);
        #pragma unroll
        for (int mi = 0; mi < 8; mi++)
            #pragma unroll
            for (int ni = 0; ni < 4; ni++)
                acc[mi][ni] = __builtin_amdgcn_mfma_f32_16x16x32_bf16(a0[mi], b0[ni], acc[mi][ni], 0, 0, 0);
        __builtin_amdgcn_s_setprio(0);
        asm volatile("s_waitcnt lgkmcnt(0)" ::: "memory");
        __builtin_amdgcn_sched_barrier(0);
        __builtin_amdgcn_s_barrier();

        if (kt + 2 < nk) STAGE_T(kt + 2, d);
        __builtin_amdgcn_s_setprio(1);
        #pragma unroll
        for (int mi = 0; mi < 8; mi++)
            #pragma unroll
            for (int ni = 0; ni < 4; ni++)
                acc[mi][ni] = __builtin_amdgcn_mfma_f32_16x16x32_bf16(a1[mi], b1[ni], acc[mi][ni], 0, 0, 0);
        __builtin_amdgcn_s_setprio(0);
        if (kt + 1 < nk) {
            if (kt + 2 < nk) asm volatile("s_waitcnt vmcnt(8)" ::: "memory");
            else             asm volatile("s_waitcnt vmcnt(0)" ::: "memory");
            __builtin_amdgcn_sched_barrier(0);
            __builtin_amdgcn_s_barrier();
        }
    }
#undef STAGE_T

    bool addBias = (blockIdx.z == 0);
    #pragma unroll
    for (int mi = 0; mi < 8; mi++) {
        #pragma unroll
        for (int ni = 0; ni < 4; ni++) {
            int col = n0 + wn + ni * 16 + lr;
            float bv = addBias ? bias[col] : 0.0f;
            #pragma unroll
            for (int r = 0; r < 4; r++) {
                int row = m0 + wm + mi * 16 + lq * 4 + r;
                atomicAdd(&outf[(size_t)row * N + col], acc[mi][ni][r] + bv);
            }
        }
    }
}

extern "C" void kernel_launch(void* const* d_in, const int* in_sizes, int n_in,
                              void* d_out, int out_size, void* d_ws, size_t ws_size,
                              hipStream_t stream) {
    const float* input = (const float*)d_in[0];
    const float* w1    = (const float*)d_in[1];
    const float* b1    = (const float*)d_in[2];
    const float* w2    = (const float*)d_in[3];
    const float* b2    = (const float*)d_in[4];
    const float* ln1g  = (const float*)d_in[5];
    const float* ln1b  = (const float*)d_in[6];
    const float* ln2g  = (const float*)d_in[7];
    const float* ln2b  = (const float*)d_in[8];
    const float* mw1   = (const float*)d_in[9];
    const float* mb1   = (const float*)d_in[10];
    const float* mw2   = (const float*)d_in[11];
    const float* mb2   = (const float*)d_in[12];
    float* out = (float*)d_out;

    // ---- workspace layout ----
    // phase 1: [mu|rs | gre | gim | fr | fi]  (66.2 MB)
    // phase 2 (aliases):[mu|rs | lnA(bf16) | w1T | w2T | mid(bf16)]
    float* ws = (float*)d_ws;
    float* mu  = ws;                       // 16384
    float* rs  = ws + 16384;               // 16384
    const size_t BASE = 32768;
    float* gre = ws + BASE;                // 4,718,592
    float* gim = gre + 4718592;            // 4,718,592
    float* fr  = ws + BASE + 2 * 4718592;  // 3,538,944
    float* fi  = fr + 3538944;             // 3,538,944
    bf16* lnA = (bf16*)(ws + BASE);                  // 12,582,912 bf16
    bf16* w1T = (bf16*)(ws + BASE + 6291456);        //  2,359,296 bf16
    bf16* w2T = (bf16*)(ws + BASE + 7471104);        //  2,359,296 bf16
    bf16* mid = (bf16*)(ws + BASE + 8650752);        // up to 16384x3072 bf16

    // chunk count for channel-MLP, from ws_size (constant across calls -> graph-safe)
    const size_t fixed_fl = BASE + 6291456 + 1179648 + 1179648;   // 8,683,520 floats
    size_t avail_fl = ws_size / 4;
    int nch;
    if      (avail_fl >= fixed_fl + 25165824) nch = 1;   // mid = 16384x3072
    else if (avail_fl >= fixed_fl + 12582912) nch = 2;   // mid =  8192x3072
    else                                      nch = 4;   // mid =  4096x3072
    int MC = 16384 / nch;

    k_ln_stats<<<4096, 256, 0, stream>>>(input, mu, rs);
    k_dft_y<<<BT_ * 32 * 3, 256, 0, stream>>>(input, mu, rs, ln1g, ln1b, gre, gim);
    k_dft_x<<<BT_ * KM_ * 3, 256, 0, stream>>>(gre, gim, fr, fi);
    k_blockmlp<<<NB_ * 36, 256, 0, stream>>>(fr, fi, w1, b1, w2, b2);
    k_idft_x<<<BT_ * KM_ * 3, 256, 0, stream>>>(fr, fi, gre, gim);   // gre/gim now hold Z
    k_idft_y_res<<<BT_ * 32 * 3, 256, 0, stream>>>(gre, gim, input, mu, rs, ln1g, ln1b, out);
    k_ln2<<<4096, 256, 0, stream>>>(out, ln2g, ln2b, lnA);
    k_transpose_cast<<<dim3(3072 / 32, 768 / 32), dim3(32, 8), 0, stream>>>(mw1, w1T, 768, 3072);
    k_transpose_cast<<<dim3(768 / 32, 3072 / 32), dim3(32, 8), 0, stream>>>(mw2, w2T, 3072, 768);
    for (int c = 0; c < nch; c++) {
        const bf16* aC = lnA + (size_t)c * MC * 768;
        float* oC = out + (size_t)c * MC * 768;
        k_gemm<true><<<dim3(MC / 256, 12), 512, 0, stream>>>(aC, w1T, mb1, MC, 3072, 768, mid, nullptr);
        k_gemm_splitk<<<dim3(MC / 256, 3, 4), 512, 0, stream>>>(mid, w2T, mb2, MC, 768, 3072, 768, oC);
    }
}

// Round 13
// 454.919 us; speedup vs baseline: 1.2184x; 1.2184x over previous
//
#include <hip/hip_runtime.h>
#include <hip/hip_bf16.h>
#include <math.h>

typedef __bf16 bf16;
typedef __bf16 bf16x8 __attribute__((ext_vector_type(8)));
typedef float f32x4 __attribute__((ext_vector_type(4)));
typedef short short8 __attribute__((ext_vector_type(8)));

#define E_ 768
#define S_ 1024
#define BT_ 16
#define KM_ 12
#define KX_ 24
#define NPOS_ 4608
#define NB_ 12

// compile-time twiddles: C32d[j]=cos(2*pi*j/32), S32d[j]=sin(2*pi*j/32).
// Indexed with wave-uniform (and, after unrolling, compile-time) j -> no trig,
// no LDS, no serial recurrence chain.
__device__ const float C32d[32] = {
    1.0f,  0.980785280f,  0.923879533f,  0.831469612f,  0.707106781f,  0.555570233f,  0.382683432f,  0.195090322f,
    0.0f, -0.195090322f, -0.382683432f, -0.555570233f, -0.707106781f, -0.831469612f, -0.923879533f, -0.980785280f,
   -1.0f, -0.980785280f, -0.923879533f, -0.831469612f, -0.707106781f, -0.555570233f, -0.382683432f, -0.195090322f,
    0.0f,  0.195090322f,  0.382683432f,  0.555570233f,  0.707106781f,  0.831469612f,  0.923879533f,  0.980785280f
};
__device__ const float S32d[32] = {
    0.0f,  0.195090322f,  0.382683432f,  0.555570233f,  0.707106781f,  0.831469612f,  0.923879533f,  0.980785280f,
    1.0f,  0.980785280f,  0.923879533f,  0.831469612f,  0.707106781f,  0.555570233f,  0.382683432f,  0.195090322f,
    0.0f, -0.195090322f, -0.382683432f, -0.555570233f, -0.707106781f, -0.831469612f, -0.923879533f, -0.980785280f,
   -1.0f, -0.980785280f, -0.923879533f, -0.831469612f, -0.707106781f, -0.555570233f, -0.382683432f, -0.195090322f
};

// tanh-form gelu, ~10 VALU ops (2 transcendental) vs erff's ~30.
__device__ __forceinline__ float gelu_fast(float x) {
    float t = x * x;
    float u = x * fmaf(t, 0.0356774081f, 0.7978845608f);  // 0.79788456*(x + 0.044715 x^3)
    float e = __expf(2.0f * u);
    float th = fmaf(-2.0f, __fdividef(1.0f, e + 1.0f), 1.0f);  // tanh(u)
    float hx = 0.5f * x;
    return fmaf(hx, th, hx);
}

// negate 8 bf16 lanes (flip sign bits) — MFMA has no subtract-accumulate
__device__ __forceinline__ bf16x8 neg8(bf16x8 v) {
    short8 s;
    __builtin_memcpy(&s, &v, 16);
    s ^= (short)0x8000;
    bf16x8 r;
    __builtin_memcpy(&r, &s, 16);
    return r;
}

// async global->LDS, 16B per lane. LDS dest is wave-uniform base + lane*16;
// global src is per-lane.
__device__ __forceinline__ void gload16(bf16* lds, const bf16* g) {
    __builtin_amdgcn_global_load_lds(
        (const __attribute__((address_space(1))) void*)g,
        (__attribute__((address_space(3))) void*)lds,
        16, 0, 0);
}

// ---------------- LN1 stats: wave-per-row (4 rows/block), float4 loads, no LDS ----------------
__global__ __launch_bounds__(256) void k_ln_stats(const float* __restrict__ x,
                                                  float* __restrict__ mu, float* __restrict__ rs) {
    int w = threadIdx.x >> 6, l = threadIdx.x & 63;
    int row = blockIdx.x * 4 + w;
    const float4* p = (const float4*)(x + (size_t)row * E_ + l * 12);
    float4 a = p[0], b = p[1], c = p[2];
    float s  = a.x + a.y + a.z + a.w + b.x + b.y + b.z + b.w + c.x + c.y + c.z + c.w;
    float ss = a.x*a.x + a.y*a.y + a.z*a.z + a.w*a.w
             + b.x*b.x + b.y*b.y + b.z*b.z + b.w*b.w
             + c.x*c.x + c.y*c.y + c.z*c.z + c.w*c.w;
    #pragma unroll
    for (int off = 32; off > 0; off >>= 1) {
        s  += __shfl_xor(s, off);
        ss += __shfl_xor(ss, off);
    }
    if (l == 0) {
        float m = s * (1.0f / E_);
        float var = ss * (1.0f / E_) - m * m;
        mu[row] = m;
        rs[row] = rsqrtf(var + 1e-5f);
    }
}

// ---------------- full LayerNorm (ln2) -> bf16: wave-per-row, vectorized ----------------
__global__ __launch_bounds__(256) void k_ln2(const float* __restrict__ x,
                                             const float* __restrict__ g,
                                             const float* __restrict__ b,
                                             bf16* __restrict__ out) {
    int w = threadIdx.x >> 6, l = threadIdx.x & 63;
    int row = blockIdx.x * 4 + w;
    int e0 = l * 12;
    const float4* p = (const float4*)(x + (size_t)row * E_ + e0);
    float4 va = p[0], vb = p[1], vc = p[2];
    float v[12] = {va.x, va.y, va.z, va.w, vb.x, vb.y, vb.z, vb.w, vc.x, vc.y, vc.z, vc.w};
    float s = 0.f, ss = 0.f;
    #pragma unroll
    for (int j = 0; j < 12; j++) { s += v[j]; ss += v[j] * v[j]; }
    #pragma unroll
    for (int off = 32; off > 0; off >>= 1) {
        s  += __shfl_xor(s, off);
        ss += __shfl_xor(ss, off);
    }
    float m = s * (1.0f / E_);
    float var = ss * (1.0f / E_) - m * m;
    float r = rsqrtf(var + 1e-5f);
    const float4* gp = (const float4*)(g + e0);
    const float4* bp = (const float4*)(b + e0);
    float4 g0 = gp[0], g1 = gp[1], g2 = gp[2];
    float4 b0 = bp[0], b1 = bp[1], b2 = bp[2];
    float gg[12] = {g0.x, g0.y, g0.z, g0.w, g1.x, g1.y, g1.z, g1.w, g2.x, g2.y, g2.z, g2.w};
    float bbv[12] = {b0.x, b0.y, b0.z, b0.w, b1.x, b1.y, b1.z, b1.w, b2.x, b2.y, b2.z, b2.w};
    bf16 ov[12];
    #pragma unroll
    for (int j = 0; j < 12; j++) ov[j] = (bf16)((v[j] - m) * r * gg[j] + bbv[j]);
    bf16* op = out + (size_t)row * E_ + e0;
    *(uint2*)(op)     = *(uint2*)&ov[0];
    *(uint2*)(op + 4) = *(uint2*)&ov[4];
    *(uint2*)(op + 8) = *(uint2*)&ov[8];
}

// ---------------- forward DFT along y (12 modes), LN1 fused; register data + const tables ----------------
__global__ __launch_bounds__(256) void k_dft_y(const float* __restrict__ inp,
                                               const float* __restrict__ mu, const float* __restrict__ rs,
                                               const float* __restrict__ g, const float* __restrict__ bb,
                                               float* __restrict__ gre, float* __restrict__ gim) {
    int bid = blockIdx.x;                 // BT_*32*3
    int ec = bid % 3, x = (bid / 3) % 32, bt = bid / 96;
    int t = threadIdx.x;
    int e = ec * 256 + t;
    float gv = g[e], bv = bb[e];
    int row0 = bt * S_ + x * 32;
    const float* base = inp + (size_t)row0 * E_ + e;
    float v[32];
    #pragma unroll
    for (int y = 0; y < 32; y++) {
        float m = mu[row0 + y], r = rs[row0 + y];
        v[y] = (base[(size_t)y * E_] - m) * r * gv + bv;
    }
    #pragma unroll
    for (int ky = 0; ky < KM_; ky++) {
        float re = 0.f, ims = 0.f;
        #pragma unroll
        for (int y = 0; y < 32; y++) {
            int j = (ky * y) & 31;
            re  = fmaf(v[y], C32d[j], re);
            ims = fmaf(v[y], S32d[j], ims);
        }
        size_t o = ((size_t)((bt * 32 + x) * KM_ + ky)) * E_ + e;
        gre[o] = re; gim[o] = -ims;       // e^{-i...}: im = -sum(v*sin)
    }
}

// ---------------- forward DFT along x (kx=5..28), scale 1/32; register data + const tables ----------------
__global__ __launch_bounds__(256) void k_dft_x(const float* __restrict__ gre, const float* __restrict__ gim,
                                               float* __restrict__ fr, float* __restrict__ fi) {
    int bid = blockIdx.x;                 // BT_*KM_*3
    int ec = bid % 3, ky = (bid / 3) % KM_, bt = bid / (3 * KM_);
    int t = threadIdx.x;
    int eo = ec * 256 + t;
    float gr[32], gi[32];
    #pragma unroll
    for (int x = 0; x < 32; x++) {
        size_t o = ((size_t)((bt * 32 + x) * KM_ + ky)) * E_ + eo;
        gr[x] = gre[o]; gi[x] = gim[o];
    }
    #pragma unroll
    for (int kxi = 0; kxi < KX_; kxi++) {
        int kx = kxi + 5;
        float re = 0.f, im = 0.f;
        #pragma unroll
        for (int x = 0; x < 32; x++) {
            int j = (kx * x) & 31;
            float c = C32d[j], s = S32d[j];
            re = fmaf(gr[x], c, re);      // (gr+i*gi)*(c - i*s)
            re = fmaf(gi[x], s, re);
            im = fmaf(gi[x], c, im);
            im = fmaf(-gr[x], s, im);
        }
        size_t p = (size_t)(bt * KX_ + kxi) * KM_ + ky;
        fr[p * E_ + eo] = re * (1.0f / 32.0f);
        fi[p * E_ + eo] = im * (1.0f / 32.0f);
    }
}

// ---------------- MFMA block-diagonal complex 2-layer MLP + softshrink (in-place fr/fi) ----------------
__global__ __launch_bounds__(256) void k_blockmlp(float* fr, float* fi,
                                                  const float* __restrict__ w1, const float* __restrict__ b1,
                                                  const float* __restrict__ w2, const float* __restrict__ b2) {
    int n = blockIdx.x / 36;
    int p0 = (blockIdx.x % 36) * 128;
    int t = threadIdx.x;
    __shared__ __align__(16) bf16 lXr[128 * 72];
    __shared__ __align__(16) bf16 lXi[128 * 72];
    __shared__ __align__(16) bf16 lW1a[64 * 72];
    __shared__ __align__(16) bf16 lW1b[64 * 72];
    __shared__ __align__(16) bf16 lW2a[64 * 72];
    __shared__ __align__(16) bf16 lW2b[64 * 72];

    {
        int o = t & 63, iq = t >> 6;
        const float* s1a = w1 + (size_t)n * 4096;
        const float* s1b = w1 + (size_t)(NB_ + n) * 4096;
        const float* s2a = w2 + (size_t)n * 4096;
        const float* s2b = w2 + (size_t)(NB_ + n) * 4096;
        #pragma unroll
        for (int ii = 0; ii < 16; ii++) {
            int i = iq * 16 + ii;
            lW1a[o * 72 + i] = (bf16)s1a[i * 64 + o];
            lW1b[o * 72 + i] = (bf16)s1b[i * 64 + o];
            lW2a[o * 72 + i] = (bf16)s2a[i * 64 + o];
            lW2b[o * 72 + i] = (bf16)s2b[i * 64 + o];
        }
    }
    {
        int ch4 = (t & 15) * 4, prow = t >> 4;
        #pragma unroll
        for (int rep = 0; rep < 8; rep++) {
            int p = rep * 16 + prow;
            size_t ga = (size_t)(p0 + p) * E_ + n * 64 + ch4;
            float4 vr = *(const float4*)&fr[ga];
            float4 vi = *(const float4*)&fi[ga];
            bf16 br[4] = {(bf16)vr.x, (bf16)vr.y, (bf16)vr.z, (bf16)vr.w};
            bf16 bi[4] = {(bf16)vi.x, (bf16)vi.y, (bf16)vi.z, (bf16)vi.w};
            *(uint2*)&lXr[p * 72 + ch4] = *(uint2*)br;
            *(uint2*)&lXi[p * 72 + ch4] = *(uint2*)bi;
        }
    }
    int w = t >> 6, l = t & 63, lr = l & 15, lq = l >> 4;
    float bias1r[4], bias1i[4], bias2r[4], bias2i[4];
    #pragma unroll
    for (int ni = 0; ni < 4; ni++) {
        int o = n * 64 + ni * 16 + lr;
        bias1r[ni] = b1[o]; bias1i[ni] = b1[NB_ * 64 + o];
        bias2r[ni] = b2[o]; bias2i[ni] = b2[NB_ * 64 + o];
    }
    __syncthreads();

    f32x4 a1r[2][4], a1i[2][4];
    #pragma unroll
    for (int mt = 0; mt < 2; mt++)
        #pragma unroll
        for (int ni = 0; ni < 4; ni++) { a1r[mt][ni] = (f32x4){0,0,0,0}; a1i[mt][ni] = (f32x4){0,0,0,0}; }
    #pragma unroll
    for (int ks = 0; ks < 2; ks++) {
        int k0 = ks * 32;
        bf16x8 xr[2], xi[2], xin[2];
        #pragma unroll
        for (int mt = 0; mt < 2; mt++) {
            int row = w * 32 + mt * 16 + lr;
            xr[mt]  = *(bf16x8*)&lXr[row * 72 + k0 + lq * 8];
            xi[mt]  = *(bf16x8*)&lXi[row * 72 + k0 + lq * 8];
            xin[mt] = neg8(xi[mt]);
        }
        #pragma unroll
        for (int ni = 0; ni < 4; ni++) {
            bf16x8 ba = *(bf16x8*)&lW1a[(ni * 16 + lr) * 72 + k0 + lq * 8];
            bf16x8 bb = *(bf16x8*)&lW1b[(ni * 16 + lr) * 72 + k0 + lq * 8];
            #pragma unroll
            for (int mt = 0; mt < 2; mt++) {
                a1r[mt][ni] = __builtin_amdgcn_mfma_f32_16x16x32_bf16(xr[mt],  ba, a1r[mt][ni], 0, 0, 0);
                a1r[mt][ni] = __builtin_amdgcn_mfma_f32_16x16x32_bf16(xin[mt], bb, a1r[mt][ni], 0, 0, 0);
                a1i[mt][ni] = __builtin_amdgcn_mfma_f32_16x16x32_bf16(xi[mt],  ba, a1i[mt][ni], 0, 0, 0);
                a1i[mt][ni] = __builtin_amdgcn_mfma_f32_16x16x32_bf16(xr[mt],  bb, a1i[mt][ni], 0, 0, 0);
            }
        }
    }
    #pragma unroll
    for (int mt = 0; mt < 2; mt++)
        #pragma unroll
        for (int ni = 0; ni < 4; ni++) {
            int o = ni * 16 + lr;
            #pragma unroll
            for (int r = 0; r < 4; r++) {
                int row = w * 32 + mt * 16 + lq * 4 + r;
                lXr[row * 72 + o] = (bf16)gelu_fast(a1r[mt][ni][r] + bias1r[ni]);
                lXi[row * 72 + o] = (bf16)gelu_fast(a1i[mt][ni][r] + bias1i[ni]);
            }
        }

    f32x4 a2r[2][4], a2i[2][4];
    #pragma unroll
    for (int mt = 0; mt < 2; mt++)
        #pragma unroll
        for (int ni = 0; ni < 4; ni++) { a2r[mt][ni] = (f32x4){0,0,0,0}; a2i[mt][ni] = (f32x4){0,0,0,0}; }
    #pragma unroll
    for (int ks = 0; ks < 2; ks++) {
        int k0 = ks * 32;
        bf16x8 xr[2], xi[2], xin[2];
        #pragma unroll
        for (int mt = 0; mt < 2; mt++) {
            int row = w * 32 + mt * 16 + lr;
            xr[mt]  = *(bf16x8*)&lXr[row * 72 + k0 + lq * 8];
            xi[mt]  = *(bf16x8*)&lXi[row * 72 + k0 + lq * 8];
            xin[mt] = neg8(xi[mt]);
        }
        #pragma unroll
        for (int ni = 0; ni < 4; ni++) {
            bf16x8 ba = *(bf16x8*)&lW2a[(ni * 16 + lr) * 72 + k0 + lq * 8];
            bf16x8 bb = *(bf16x8*)&lW2b[(ni * 16 + lr) * 72 + k0 + lq * 8];
            #pragma unroll
            for (int mt = 0; mt < 2; mt++) {
                a2r[mt][ni] = __builtin_amdgcn_mfma_f32_16x16x32_bf16(xr[mt],  ba, a2r[mt][ni], 0, 0, 0);
                a2r[mt][ni] = __builtin_amdgcn_mfma_f32_16x16x32_bf16(xin[mt], bb, a2r[mt][ni], 0, 0, 0);
                a2i[mt][ni] = __builtin_amdgcn_mfma_f32_16x16x32_bf16(xi[mt],  ba, a2i[mt][ni], 0, 0, 0);
                a2i[mt][ni] = __builtin_amdgcn_mfma_f32_16x16x32_bf16(xr[mt],  bb, a2i[mt][ni], 0, 0, 0);
            }
        }
    }
    #pragma unroll
    for (int mt = 0; mt < 2; mt++)
        #pragma unroll
        for (int ni = 0; ni < 4; ni++) {
            int o = ni * 16 + lr;
            #pragma unroll
            for (int r = 0; r < 4; r++) {
                int row = w * 32 + mt * 16 + lq * 4 + r;
                float vr = a2r[mt][ni][r] + bias2r[ni];
                float vi = a2i[mt][ni][r] + bias2i[ni];
                vr = (vr > 0.01f) ? vr - 0.01f : ((vr < -0.01f) ? vr + 0.01f : 0.0f);
                vi = (vi > 0.01f) ? vi - 0.01f : ((vi < -0.01f) ? vi + 0.01f : 0.0f);
                size_t ga = (size_t)(p0 + row) * E_ + n * 64 + o;
                fr[ga] = vr;
                fi[ga] = vi;
            }
        }
}

// ---------------- inverse DFT along x (24 modes -> 32 x); register data + const tables ----------------
__global__ __launch_bounds__(256) void k_idft_x(const float* __restrict__ pr_, const float* __restrict__ pi_,
                                                float* __restrict__ zre, float* __restrict__ zim) {
    int bid = blockIdx.x;                 // BT_*KM_*3
    int ec = bid % 3, ky = (bid / 3) % KM_, bt = bid / (3 * KM_);
    int t = threadIdx.x;
    int eo = ec * 256 + t;
    float pr[KX_], pi[KX_];
    #pragma unroll
    for (int kxi = 0; kxi < KX_; kxi++) {
        size_t p = (size_t)(bt * KX_ + kxi) * KM_ + ky;
        pr[kxi] = pr_[p * E_ + eo];
        pi[kxi] = pi_[p * E_ + eo];
    }
    #pragma unroll
    for (int x = 0; x < 32; x++) {
        float re = 0.f, im = 0.f;
        #pragma unroll
        for (int kxi = 0; kxi < KX_; kxi++) {
            int j = ((kxi + 5) * x) & 31;
            float c = C32d[j], s = S32d[j];
            re = fmaf(pr[kxi], c, re);    // (pr+i*pi)*(c + i*s)
            re = fmaf(-pi[kxi], s, re);
            im = fmaf(pr[kxi], s, im);
            im = fmaf(pi[kxi], c, im);
        }
        size_t zo = ((size_t)((bt * 32 + x) * KM_ + ky)) * E_ + eo;
        zre[zo] = re; zim[zo] = im;
    }
}

// ---------------- inverse rfft along y + residuals; register data + const tables ----------------
__global__ __launch_bounds__(256) void k_idft_y_res(const float* __restrict__ zre, const float* __restrict__ zim,
                                                    const float* __restrict__ inp,
                                                    const float* __restrict__ mu, const float* __restrict__ rs,
                                                    const float* __restrict__ g, const float* __restrict__ bb,
                                                    float* __restrict__ out) {
    int bid = blockIdx.x;                 // BT_*32*3
    int ec = bid % 3, x = (bid / 3) % 32, bt = bid / 96;
    int t = threadIdx.x;
    int e = ec * 256 + t;
    float zr[KM_], zi[KM_];
    #pragma unroll
    for (int ky = 0; ky < KM_; ky++) {
        size_t zo = ((size_t)((bt * 32 + x) * KM_ + ky)) * E_ + e;
        zr[ky] = zre[zo];
        zi[ky] = zim[zo];
    }
    float gv = g[e], bv = bb[e];
    int row0 = bt * S_ + x * 32;
    #pragma unroll
    for (int y = 0; y < 32; y++) {
        float v = zr[0];                  // ky=0: Re only (irfft drops Im of DC)
        #pragma unroll
        for (int ky = 1; ky < KM_; ky++) {
            int j = (ky * y) & 31;
            v = fmaf(zr[ky], 2.0f * C32d[j], v);
            v = fmaf(zi[ky], -2.0f * S32d[j], v);
        }
        v *= (1.0f / 32.0f);
        size_t o = (size_t)(row0 + y) * E_ + e;
        float iv = inp[o];
        float m = mu[row0 + y], r = rs[row0 + y];
        out[o] = v + ((iv - m) * r * gv + bv) + iv;
    }
}

// ---------------- fp32 [R][C] -> bf16 [C][R] transpose+cast ----------------
__global__ void k_transpose_cast(const float* __restrict__ src, bf16* __restrict__ dst, int R, int C) {
    __shared__ float tile[32][33];
    int c0 = blockIdx.x * 32, r0 = blockIdx.y * 32;
    int tx = threadIdx.x, ty = threadIdx.y;
    #pragma unroll
    for (int j = 0; j < 32; j += 8)
        tile[ty + j][tx] = src[(size_t)(r0 + ty + j) * C + c0 + tx];
    __syncthreads();
    #pragma unroll
    for (int j = 0; j < 32; j += 8)
        dst[(size_t)(c0 + ty + j) * R + r0 + tx] = (bf16)tile[tx][ty + j];
}

// ---------------- bf16 MFMA GEMM, 256x256 tile, BK=64, counted-vmcnt pipeline ----------------
// (round-5 kernel, verified: 0 bank conflicts, passed. Used for BOTH GEMMs.)
template<bool FUSE_GELU>
__global__ __launch_bounds__(512, 2) void k_gemm(const bf16* __restrict__ A, const bf16* __restrict__ Bt,
                                                 const float* __restrict__ bias, int M, int N, int K,
                                                 bf16* __restrict__ outb, float* __restrict__ outf) {
    __shared__ __align__(16) bf16 lA[2][256 * 64];
    __shared__ __align__(16) bf16 lB[2][256 * 64];
    int t = threadIdx.x;
    int m0 = blockIdx.x * 256, n0 = blockIdx.y * 256;
    int w = t >> 6, l = t & 63;
    int wm = (w >> 2) * 128, wn = (w & 3) * 64;
    int lr = l & 15, lq = l >> 4;
    int s0 = (lq ^ (lr & 7)) * 8;          // phys 16B-slot for ks=0, in bf16 elems
    int s1 = s0 ^ 32;                      // ks=1: logical slot +4 -> XOR bit2 (32 elems)

    int sil  = w * 8 + (l >> 3);           // row within line
    int gcol = ((l & 7) ^ ((l >> 3) & 7)) * 8;
    const bf16* pa = A  + (size_t)(m0 + sil) * K + gcol;
    const bf16* pb = Bt + (size_t)(n0 + sil) * K + gcol;
    int lofs = (w * 8) * 64;               // wave-uniform LDS base (elems)

    f32x4 acc[8][4];
    #pragma unroll
    for (int i = 0; i < 8; i++)
        #pragma unroll
        for (int j = 0; j < 4; j++)
            acc[i][j] = (f32x4){0.f, 0.f, 0.f, 0.f};

    int nk = K / 64;
#define STAGE_T(T, d) do { const size_t _ko = (size_t)(T) * 64;                  \
        gload16(&lA[d][lofs],            pa + _ko);                              \
        gload16(&lA[d][lofs + 4096],     pa + (size_t)64  * K + _ko);            \
        gload16(&lA[d][lofs + 8192],     pa + (size_t)128 * K + _ko);            \
        gload16(&lA[d][lofs + 12288],    pa + (size_t)192 * K + _ko);            \
        gload16(&lB[d][lofs],            pb + _ko);                              \
        gload16(&lB[d][lofs + 4096],     pb + (size_t)64  * K + _ko);            \
        gload16(&lB[d][lofs + 8192],     pb + (size_t)128 * K + _ko);            \
        gload16(&lB[d][lofs + 12288],    pb + (size_t)192 * K + _ko);            \
    } while (0)

    STAGE_T(0, 0);
    STAGE_T(1, 1);
    asm volatile("s_waitcnt vmcnt(8)" ::: "memory");   // tile0 landed; tile1's 8 in flight
    __builtin_amdgcn_sched_barrier(0);
    __builtin_amdgcn_s_barrier();

    for (int kt = 0; kt < nk; kt++) {
        int d = kt & 1;
        bf16x8 a0[8], a1[8], b0[4], b1[4];
        #pragma unroll
        for (int ni = 0; ni < 4; ni++) {
            int ro = (wn + ni * 16 + lr) * 64;
            b0[ni] = *(bf16x8*)&lB[d][ro + s0];
            b1[ni] = *(bf16x8*)&lB[d][ro + s1];
        }
        #pragma unroll
        for (int mi = 0; mi < 8; mi++) {
            int ro = (wm + mi * 16 + lr) * 64;
            a0[mi] = *(bf16x8*)&lA[d][ro + s0];
            a1[mi] = *(bf16x8*)&lA[d][ro + s1];
        }
        __builtin_amdgcn_s_setprio(1);
        #pragma unroll
        for (int mi = 0; mi < 8; mi++)
            #pragma unroll
            for (int ni = 0; ni < 4; ni++)
                acc[mi][ni] = __builtin_amdgcn_mfma_f32_16x16x32_bf16(a0[mi], b0[ni], acc[mi][ni], 0, 0, 0);
        __builtin_amdgcn_s_setprio(0);
        asm volatile("s_waitcnt lgkmcnt(0)" ::: "memory");   // all 24 reads in regs
        __builtin_amdgcn_sched_barrier(0);
        __builtin_amdgcn_s_barrier();                        // dbuf[d] reads done block-wide

        if (kt + 2 < nk) STAGE_T(kt + 2, d);                 // into dead dbuf[d]
        __builtin_amdgcn_s_setprio(1);
        #pragma unroll
        for (int mi = 0; mi < 8; mi++)
            #pragma unroll
            for (int ni = 0; ni < 4; ni++)
                acc[mi][ni] = __builtin_amdgcn_mfma_f32_16x16x32_bf16(a1[mi], b1[ni], acc[mi][ni], 0, 0, 0);
        __builtin_amdgcn_s_setprio(0);
        if (kt + 1 < nk) {
            if (kt + 2 < nk) asm volatile("s_waitcnt vmcnt(8)" ::: "memory");  // tile kt+1 landed
            else             asm volatile("s_waitcnt vmcnt(0)" ::: "memory");  // tail drain
            __builtin_amdgcn_sched_barrier(0);
            __builtin_amdgcn_s_barrier();
        }
    }
#undef STAGE_T

    #pragma unroll
    for (int mi = 0; mi < 8; mi++) {
        #pragma unroll
        for (int ni = 0; ni < 4; ni++) {
            int col = n0 + wn + ni * 16 + lr;
            float bv = bias[col];
            #pragma unroll
            for (int r = 0; r < 4; r++) {
                int row = m0 + wm + mi * 16 + lq * 4 + r;
                float v = acc[mi][ni][r] + bv;
                if (FUSE_GELU) {
                    outb[(size_t)row * N + col] = (bf16)gelu_fast(v);
                } else {
                    size_t oo = (size_t)row * N + col;
                    outf[oo] = v + outf[oo];
                }
            }
        }
    }
}

extern "C" void kernel_launch(void* const* d_in, const int* in_sizes, int n_in,
                              void* d_out, int out_size, void* d_ws, size_t ws_size,
                              hipStream_t stream) {
    const float* input = (const float*)d_in[0];
    const float* w1    = (const float*)d_in[1];
    const float* b1    = (const float*)d_in[2];
    const float* w2    = (const float*)d_in[3];
    const float* b2    = (const float*)d_in[4];
    const float* ln1g  = (const float*)d_in[5];
    const float* ln1b  = (const float*)d_in[6];
    const float* ln2g  = (const float*)d_in[7];
    const float* ln2b  = (const float*)d_in[8];
    const float* mw1   = (const float*)d_in[9];
    const float* mb1   = (const float*)d_in[10];
    const float* mw2   = (const float*)d_in[11];
    const float* mb2   = (const float*)d_in[12];
    float* out = (float*)d_out;

    // ---- workspace layout ----
    // phase 1: [mu|rs | gre | gim | fr | fi]  (66.2 MB)
    // phase 2 (aliases):[mu|rs | lnA(bf16) | w1T | w2T | mid(bf16)]
    float* ws = (float*)d_ws;
    float* mu  = ws;                       // 16384
    float* rs  = ws + 16384;               // 16384
    const size_t BASE = 32768;
    float* gre = ws + BASE;                // 4,718,592
    float* gim = gre + 4718592;            // 4,718,592
    float* fr  = ws + BASE + 2 * 4718592;  // 3,538,944
    float* fi  = fr + 3538944;             // 3,538,944
    bf16* lnA = (bf16*)(ws + BASE);                  // 12,582,912 bf16
    bf16* w1T = (bf16*)(ws + BASE + 6291456);        //  2,359,296 bf16
    bf16* w2T = (bf16*)(ws + BASE + 7471104);        //  2,359,296 bf16
    bf16* mid = (bf16*)(ws + BASE + 8650752);        // up to 16384x3072 bf16

    // chunk count for channel-MLP, from ws_size (constant across calls -> graph-safe)
    const size_t fixed_fl = BASE + 6291456 + 1179648 + 1179648;   // 8,683,520 floats
    size_t avail_fl = ws_size / 4;
    int nch;
    if      (avail_fl >= fixed_fl + 25165824) nch = 1;   // mid = 16384x3072
    else if (avail_fl >= fixed_fl + 12582912) nch = 2;   // mid =  8192x3072
    else                                      nch = 4;   // mid =  4096x3072
    int MC = 16384 / nch;

    k_ln_stats<<<4096, 256, 0, stream>>>(input, mu, rs);
    k_dft_y<<<BT_ * 32 * 3, 256, 0, stream>>>(input, mu, rs, ln1g, ln1b, gre, gim);
    k_dft_x<<<BT_ * KM_ * 3, 256, 0, stream>>>(gre, gim, fr, fi);
    k_blockmlp<<<NB_ * 36, 256, 0, stream>>>(fr, fi, w1, b1, w2, b2);
    k_idft_x<<<BT_ * KM_ * 3, 256, 0, stream>>>(fr, fi, gre, gim);   // gre/gim now hold Z
    k_idft_y_res<<<BT_ * 32 * 3, 256, 0, stream>>>(gre, gim, input, mu, rs, ln1g, ln1b, out);
    k_ln2<<<4096, 256, 0, stream>>>(out, ln2g, ln2b, lnA);
    k_transpose_cast<<<dim3(3072 / 32, 768 / 32), dim3(32, 8), 0, stream>>>(mw1, w1T, 768, 3072);
    k_transpose_cast<<<dim3(768 / 32, 3072 / 32), dim3(32, 8), 0, stream>>>(mw2, w2T, 3072, 768);
    for (int c = 0; c < nch; c++) {
        const bf16* aC = lnA + (size_t)c * MC * 768;
        float* oC = out + (size_t)c * MC * 768;
        k_gemm<true><<<dim3(MC / 256, 12), 512, 0, stream>>>(aC, w1T, mb1, MC, 3072, 768, mid, nullptr);
        k_gemm<false><<<dim3(MC / 256, 3), 512, 0, stream>>>(mid, w2T, mb2, MC, 768, 3072, nullptr, oC);
    }
}